// Round 12
// baseline (3151.944 us; speedup 1.0000x reference)
//
#include <hip/hip_runtime.h>
#include <cmath>

// ---------------- problem constants ----------------
#define BZ    32
#define NP    196
#define DDIM  768
#define NHEAD 12
#define MDIM  192
#define NLAY  6
#define FFDIM 3072
#define HEADU 512
#define NCLS  1000
#define KHEAD 150528      // NP*DDIM
#define BND   4816896     // BZ*NP*DDIM
#define NPART 294         // partial-stat slots for 294-block GEMM producers
#define NPARTF 4704       // partial-stat slots for ffn2_finish producer

typedef __bf16 bf16_t;
typedef __bf16 bf16x8 __attribute__((ext_vector_type(8)));
typedef __bf16 bf16x4 __attribute__((ext_vector_type(4)));
typedef float  f32x4  __attribute__((ext_vector_type(4)));
typedef float  f32x2  __attribute__((ext_vector_type(2)));

// ---------------- workspace layout (BYTE offsets) ----------------
#define OB_X      0L
#define OB_R      19267584L
#define OB_XB     38535168L
#define OB_XQKV   48168960L     // [6272][6912] bf16; first 38.5MB aliases H1/PATB
#define OB_P0     86704128L     // fp32 FFN2 partials, 2 x 19,267,584 (inside XQKV slack)
#define OB_O      165543936L
#define OB_T      194641920L
#define OB_WQKV   197050368L
#define OB_WO1    260751360L
#define OB_WO2    268025856L
#define OB_WD1    269795328L
#define OB_WD2    298106880L
#define OB_WPAT   326418432L
#define OB_BQKV   327598080L
#define OB_OB1T   327763968L
#define OB_RED    328667136L    // 2 x 4704 fp32
#define OB_FEAT   328704768L

#define ATTN_LDSP   93184
#define ATTN_LDS    143360
#define G256_LDS    98304
#define XROW        13824

__device__ __forceinline__ float gelu_exact(float x){
    return 0.5f * x * (1.0f + erff(x * 0.70710678118654752f));
}

__device__ __forceinline__ void gld16(const void* g, void* l){
    __builtin_amdgcn_global_load_lds((const __attribute__((address_space(1))) void*)g,
                                     (__attribute__((address_space(3))) void*)l, 16, 0, 0);
}

// ---------------- patch extraction (fp32 -> bf16) ----------------
__global__ void __launch_bounds__(256)
patch_extract_k(const float* __restrict__ img, bf16_t* __restrict__ out)
{
    long idx = (long)blockIdx.x * 256 + threadIdx.x;
    if (idx >= (long)BND) return;
    int k = (int)(idx % DDIM);
    long bn = idx / DDIM;
    int n = (int)(bn % NP);
    int b = (int)(bn / NP);
    int c  = k % 3;
    int pj = (k / 3) % 16;
    int pi = k / 48;
    int gi = n / 14, gj = n % 14;
    long src = (((long)(b * 224 + gi * 16 + pi)) * 224 + (gj * 16 + pj)) * 3 + c;
    out[idx] = (bf16_t)img[src];
}

// ---------------- weight convert+transpose fp32->bf16 (layer-batched) --------
__global__ void __launch_bounds__(256)
wconv_k(const float* __restrict__ in, bf16_t* __restrict__ out,
        int IR, int IC, long OLD, int perm, int padTo, long inZ, long outZ)
{
    __shared__ float tile[32][33];
    int tid = threadIdx.x, tx = tid & 31, ty = tid >> 5;
    int c0 = blockIdx.x * 32, r0 = blockIdx.y * 32;
    const float* inz = in + (long)blockIdx.z * inZ;
    bf16_t* outz = out + (long)blockIdx.z * outZ;
    #pragma unroll
    for (int i = 0; i < 4; i++){
        int r = r0 + ty + 8*i, c = c0 + tx;
        tile[ty + 8*i][tx] = (r < IR && c < IC) ? inz[(long)r * IC + c] : 0.f;
    }
    __syncthreads();
    #pragma unroll
    for (int i = 0; i < 4; i++){
        int c = c0 + ty + 8*i, r = r0 + tx;
        if (c < IC && r < padTo){
            long pc = perm ? (long)(c % 12) * 192 + c / 12 : (long)c;
            outz[pc * OLD + r] = (bf16_t)tile[tx][ty + 8*i];
        }
    }
}

// ---------------- gather QKV bias into [6][6912] ----------------
__global__ void __launch_bounds__(256)
gather_bias_k(const float* __restrict__ qb, const float* __restrict__ kb,
              const float* __restrict__ vb, float* __restrict__ out)
{
    int tid = blockIdx.x * 256 + threadIdx.x;
    int l = blockIdx.y;
    if (tid >= 6912) return;
    int g = tid / 2304, w = tid % 2304;
    int h = w / 192, m = w % 192;
    const float* src = (g == 0) ? qb : (g == 1) ? kb : vb;
    out[l*6912 + tid] = src[l*2304 + m * 12 + h];
}

// ---------------- transpose ob1 [6][192][196] -> [6][196][192] fp32 ----------
__global__ void __launch_bounds__(256)
tr_bias_k(const float* __restrict__ ob1, float* __restrict__ out)
{
    int idx = blockIdx.x * 256 + threadIdx.x;
    int l = blockIdx.y;
    if (idx >= 37632) return;
    int n = idx / 192, m = idx - n*192;
    out[(long)l*37632 + idx] = ob1[(long)l*37632 + m*196 + n];
}

// ---------------- zero O pad columns [2352,2368) ----------------
__global__ void __launch_bounds__(256)
zero_pad_o_k(bf16_t* __restrict__ o)
{
    int idx = blockIdx.x * 256 + threadIdx.x;
    if (idx >= 6144*16) return;
    int r = idx >> 4, j = idx & 15;
    o[(long)r * 2368 + 2352 + j] = (bf16_t)0.f;
}

// ---------------- global layernorm apply (reduces npart partials inline) -----
__global__ void __launch_bounds__(256)
ln_apply_k(const float* __restrict__ x, bf16_t* __restrict__ yb, float* __restrict__ yf,
           const float* __restrict__ psum, const float* __restrict__ psq, int npart)
{
    __shared__ float sred[8];
    int tid = threadIdx.x;
    float s = 0.f, q = 0.f;
    for (int i = tid; i < npart; i += 256){ s += psum[i]; q += psq[i]; }
    #pragma unroll
    for (int off = 32; off > 0; off >>= 1){ s += __shfl_xor(s, off); q += __shfl_xor(q, off); }
    if ((tid & 63) == 0){ sred[(tid>>6)*2] = s; sred[(tid>>6)*2+1] = q; }
    __syncthreads();
    s = sred[0] + sred[2] + sred[4] + sred[6];
    q = sred[1] + sred[3] + sred[5] + sred[7];
    float mean = s / (float)BND;
    float inv  = rsqrtf(q / (float)BND - mean*mean + 1e-6f);

    long i = (long)blockIdx.x * 256 + tid;
    if (i >= BND / 4) return;
    float4 v = ((const float4*)x)[i];
    v.x = (v.x - mean) * inv;
    v.y = (v.y - mean) * inv;
    v.z = (v.z - mean) * inv;
    v.w = (v.w - mean) * inv;
    bf16x4 o4 = { (bf16_t)v.x, (bf16_t)v.y, (bf16_t)v.z, (bf16_t)v.w };
    ((bf16x4*)yb)[i] = o4;
    if (yf) ((float4*)yf)[i] = v;
}

// ---------------- FFN2 finish: X = gelu(P0+P1+d2b) + R, + LN partials -------
__global__ void __launch_bounds__(256)
ffn2_finish_k(const float* __restrict__ P, const float* __restrict__ R,
              const float* __restrict__ d2b, float* __restrict__ X,
              float* __restrict__ psum, float* __restrict__ psq)
{
    __shared__ float redbuf[8];
    int tid = threadIdx.x;
    long i = (long)blockIdx.x * 256 + tid;    // f32x4 index; grid covers BND/4 exactly
    float4 a = ((const float4*)P)[i];
    float4 b = ((const float4*)(P + 4816896))[i];
    float4 r = ((const float4*)R)[i];
    int col = (int)((i * 4) % 768);
    float v0 = gelu_exact(a.x + b.x + d2b[col])     + r.x;
    float v1 = gelu_exact(a.y + b.y + d2b[col + 1]) + r.y;
    float v2 = gelu_exact(a.z + b.z + d2b[col + 2]) + r.z;
    float v3 = gelu_exact(a.w + b.w + d2b[col + 3]) + r.w;
    float4 o; o.x = v0; o.y = v1; o.z = v2; o.w = v3;
    ((float4*)X)[i] = o;
    float rs = v0 + v1 + v2 + v3;
    float rq = v0*v0 + v1*v1 + v2*v2 + v3*v3;
    #pragma unroll
    for (int off = 32; off > 0; off >>= 1){ rs += __shfl_xor(rs, off); rq += __shfl_xor(rq, off); }
    if ((tid & 63) == 0){ redbuf[(tid>>6)*2] = rs; redbuf[(tid>>6)*2+1] = rq; }
    __syncthreads();
    if (tid == 0){
        psum[blockIdx.x] = redbuf[0] + redbuf[2] + redbuf[4] + redbuf[6];
        psq[blockIdx.x]  = redbuf[1] + redbuf[3] + redbuf[5] + redbuf[7];
    }
}

// ---------------- fused attention (V^T built in-kernel from XQKV) ----------------
__global__ void __launch_bounds__(256)
attn_fused_k(const bf16_t* __restrict__ XQKV, bf16_t* __restrict__ O)
{
    extern __shared__ char lds[];
    const int tid = threadIdx.x, lane = tid & 63, w = tid >> 6;
    const int fr = lane & 15, kc = lane >> 4;
    const int s = blockIdx.y, qhalf = blockIdx.x;
    const int q0 = qhalf * 112;
    const int b = s & 31, h = s >> 5;
    const float scale = 0.03608439182435161f;   // 1/sqrt(768)
    const char* Xb = (const char*)XQKV + (long)(b*196) * XROW;
    const char* Qs = Xb + h*384;
    const char* Ks = Xb + 4608 + h*384;
    const char* Vsrc = Xb + 9216 + h*384;

    // ---- stage K rows (448B LDS rows, src pre-swizzled)
    for (int t = 0; t < 23; t++){
        int idx = t*256 + tid;
        if (idx < 5824){
            int row = idx / 28, sl = idx - row*28;
            bool val = (sl < 24) && (row < 196);
            const char* src = Ks + (val ? ((long)row*XROW + ((sl*16) ^ ((row & 7) << 4))) : 0);
            gld16(src, lds + idx*16);
        }
    }
    asm volatile("s_waitcnt vmcnt(0)");
    __syncthreads();

    float pv_all[2][13][4];
    #pragma unroll
    for (int ii = 0; ii < 2; ii++){
        int i = w + ii*4;
        if (i >= 7) continue;
        f32x4 sa[13];
        #pragma unroll
        for (int f = 0; f < 13; f++) sa[f] = (f32x4){0.f,0.f,0.f,0.f};
        int qr = q0 + i*16 + fr; if (qr > 195) qr = 195;
        #pragma unroll
        for (int c = 0; c < 6; c++){
            bf16x8 av = *(const bf16x8*)(Qs + (long)qr*XROW + c*64 + kc*16);
            #pragma unroll
            for (int f = 0; f < 13; f++){
                int krow = f*16 + fr;
                bf16x8 bv = *(const bf16x8*)(lds + krow*448 + ((c*64 + kc*16) ^ ((krow & 7) << 4)));
                sa[f] = __builtin_amdgcn_mfma_f32_16x16x32_bf16(av, bv, sa[f], 0, 0, 0);
            }
        }
        #pragma unroll
        for (int r = 0; r < 4; r++){
            float mx = -1e30f;
            #pragma unroll
            for (int f = 0; f < 13; f++)
                if (f*16 + fr < 196) mx = fmaxf(mx, sa[f][r] * scale);
            mx = fmaxf(mx, __shfl_xor(mx, 1));
            mx = fmaxf(mx, __shfl_xor(mx, 2));
            mx = fmaxf(mx, __shfl_xor(mx, 4));
            mx = fmaxf(mx, __shfl_xor(mx, 8));
            float sum = 0.f;
            #pragma unroll
            for (int f = 0; f < 13; f++){
                float pv = (f*16 + fr < 196) ? __expf(sa[f][r] * scale - mx) : 0.f;
                pv_all[ii][f][r] = pv; sum += pv;
            }
            sum += __shfl_xor(sum, 1);
            sum += __shfl_xor(sum, 2);
            sum += __shfl_xor(sum, 4);
            sum += __shfl_xor(sum, 8);
            float inv = 1.f / sum;
            #pragma unroll
            for (int f = 0; f < 13; f++) pv_all[ii][f][r] *= inv;
        }
        #pragma unroll
        for (int f = 0; f < 13; f++)
            #pragma unroll
            for (int r = 0; r < 4; r++){
                int row = i*16 + kc*4 + r;
                int cb = (f*16 + fr) * 2;
                int a = ATTN_LDSP + row*448 + (cb < 384 ? (cb ^ ((row & 7) << 4)) : cb);
                *(bf16_t*)(lds + a) = (bf16_t)pv_all[ii][f][r];
            }
        if (lane < 32){
            int row = i*16 + (lane >> 1);
            *(f32x4*)(lds + ATTN_LDSP + row*448 + 416 + (lane & 1)*16) = (f32x4){0.f,0.f,0.f,0.f};
        }
    }
    __syncthreads();   // all K reads + P writes done; area A now free

    // ---- transposed V stage: V^T rows m (448B, XOR-swizzled) into area A
    // cols n'>=196 left garbage -> masked by zeroed P columns in the PV product.
    for (int t = 0; t < 19; t++){
        int idx = t*256 + tid;
        if (idx < 4704){
            int np_ = idx / 24, ch = idx - np_*24;      // V row n', 16B chunk (m = ch*8+e)
            bf16x8 v = *(const bf16x8*)(Vsrc + (long)np_*XROW + ch*16);
            int cbase = (np_ >> 3) << 4;
            int sub = (np_*2) & 15;
            #pragma unroll
            for (int e = 0; e < 8; e++){
                int m = ch*8 + e;
                int cb = (cbase < 384) ? (cbase ^ (e << 4)) : cbase;
                *(bf16_t*)(lds + m*448 + cb + sub) = v[e];
            }
        }
    }
    __syncthreads();

    // ---- PV
    f32x4 oa2[2][12];
    #pragma unroll
    for (int ii = 0; ii < 2; ii++){
        int i = w + ii*4;
        #pragma unroll
        for (int f = 0; f < 12; f++) oa2[ii][f] = (f32x4){0.f,0.f,0.f,0.f};
        if (i >= 7) continue;
        #pragma unroll
        for (int c = 0; c < 7; c++){
            int prow = i*16 + fr;
            int cb = c*64 + kc*16;
            int acb = (cb < 384) ? (cb ^ ((prow & 7) << 4)) : cb;
            bf16x8 av = *(const bf16x8*)(lds + ATTN_LDSP + prow*448 + acb);
            #pragma unroll
            for (int f = 0; f < 12; f++){
                int vrow = f*16 + fr;
                int bcb = (cb < 384) ? (cb ^ ((vrow & 7) << 4)) : cb;
                bf16x8 bv = *(const bf16x8*)(lds + vrow*448 + bcb);
                oa2[ii][f] = __builtin_amdgcn_mfma_f32_16x16x32_bf16(av, bv, oa2[ii][f], 0, 0, 0);
            }
        }
    }
    __syncthreads();

    #pragma unroll
    for (int ii = 0; ii < 2; ii++){
        int i = w + ii*4;
        if (i >= 7) continue;
        #pragma unroll
        for (int f = 0; f < 12; f++){
            int m = f*16 + fr;
            #pragma unroll
            for (int r = 0; r < 4; r++){
                int nl = i*16 + kc*4 + r;
                *(bf16_t*)(lds + m*232 + nl*2) = (bf16_t)oa2[ii][f][r];
            }
        }
    }
    __syncthreads();
    const int nch = (qhalf == 0) ? 28 : 21;
    const int total = 192 * nch;
    char* ob = (char*)O + ((long)(b*192))*4736 + ((long)(h*196 + q0))*2;
    for (int idx = tid; idx < total; idx += 256){
        int m = idx / nch, ch = idx - m*nch;
        f32x2 v2 = *(const f32x2*)(lds + m*232 + ch*8);
        *(f32x2*)(ob + (long)m*4736 + ch*8) = v2;
    }
}

// ---------------- 256x256-tile MFMA GEMM, 8 waves, BK=32, triple-buffered ----
__global__ void __launch_bounds__(512, 2)
gemm256_k(const bf16_t* __restrict__ A, long ldA,
          const bf16_t* __restrict__ B, long ldB,
          bf16_t* __restrict__ C, long ldC,
          const float* __restrict__ bias1,
          int Md, int Nd, int Kd, int G, int doGelu)
{
    extern __shared__ char gsm[];           // 96 KiB: 3 bufs x (A 16K + B 16K)
    const int tid = threadIdx.x;
    const int lane = tid & 63, w = tid >> 6;
    const int wm = w >> 2, wn = w & 3;

    int gx = gridDim.x, gy = gridDim.y;
    int n2d = gx * gy;
    int flat = blockIdx.x + gx * blockIdx.y;
    int q8 = n2d >> 3, r8 = n2d & 7;
    int xcd = flat & 7, pos = flat >> 3;
    int lid = (xcd < r8 ? xcd*(q8+1) : r8*(q8+1) + (xcd-r8)*q8) + pos;
    int fullg = gx / G;
    int fullsz = fullg * G * gy;
    int bx, by;
    if (lid < fullsz){
        int gsz = G * gy;
        int g = lid / gsz, rem = lid - g*gsz;
        by = rem / G; bx = g*G + (rem - by*G);
    } else {
        int tw = gx - fullg*G;
        int rem = lid - fullsz;
        by = rem / tw; bx = fullg*G + (rem - by*tw);
    }
    const int row0 = by * 256, col0 = bx * 256;

    f32x4 acc[8][4];
    #pragma unroll
    for (int i = 0; i < 8; i++)
        #pragma unroll
        for (int j = 0; j < 4; j++)
            acc[i][j] = (f32x4){0.f, 0.f, 0.f, 0.f};

    const int fr = lane & 15, kc = lane >> 4;
    const int swz = (fr >> 1) & 3;
    int aOff[8], bOff[4];
    #pragma unroll
    for (int i = 0; i < 8; i++)
        aOff[i] = (wm*128 + i*16 + fr) * 64 + ((kc ^ swz) << 4);
    #pragma unroll
    for (int j = 0; j < 4; j++)
        bOff[j] = (wn*64 + j*16 + fr) * 64 + ((kc ^ swz) << 4);

    auto stage = [&](int buf, int kt){
        long kOff = (long)kt * 32;
        char* base = gsm + buf * 32768;
        #pragma unroll
        for (int r = 0; r < 2; r++){
            int idx = r*512 + tid;
            int row = idx >> 2, cp = idx & 3;
            int cc = cp ^ ((row >> 1) & 3);
            int ar = row0 + row; if (ar >= Md) ar = Md - 1;
            int br = col0 + row; if (br >= Nd) br = Nd - 1;
            gld16((const void*)(A + (long)ar*ldA + kOff + cc*8), (void*)(base + row*64 + cp*16));
            gld16((const void*)(B + (long)br*ldB + kOff + cc*8), (void*)(base + 16384 + row*64 + cp*16));
        }
    };

    const int nt = Kd >> 5;
    stage(0, 0);
    stage(1, 1);
    asm volatile("s_waitcnt vmcnt(4)" ::: "memory");
    __builtin_amdgcn_s_barrier();
    __builtin_amdgcn_sched_barrier(0);

    for (int t = 0; t < nt; t++){
        int cur = t % 3;
        if (t + 2 < nt) stage((t + 2) % 3, t + 2);
        const char* baseA = gsm + cur * 32768;
        const char* baseB = baseA + 16384;
        bf16x8 av[8], bv[4];
        #pragma unroll
        for (int i = 0; i < 8; i++) av[i] = *(const bf16x8*)(baseA + aOff[i]);
        #pragma unroll
        for (int j = 0; j < 4; j++) bv[j] = *(const bf16x8*)(baseB + bOff[j]);
        __builtin_amdgcn_s_setprio(1);
        #pragma unroll
        for (int i = 0; i < 8; i++)
            #pragma unroll
            for (int j = 0; j < 4; j++)
                acc[i][j] = __builtin_amdgcn_mfma_f32_16x16x32_bf16(av[i], bv[j], acc[i][j], 0, 0, 0);
        __builtin_amdgcn_s_setprio(0);
        if (t + 2 < nt)      asm volatile("s_waitcnt vmcnt(4)" ::: "memory");
        else if (t + 1 < nt) asm volatile("s_waitcnt vmcnt(0)" ::: "memory");
        __builtin_amdgcn_s_barrier();
        __builtin_amdgcn_sched_barrier(0);
    }

    #pragma unroll
    for (int i = 0; i < 8; i++){
        int gmb = row0 + wm*128 + i*16 + kc*4;
        #pragma unroll
        for (int j = 0; j < 4; j++){
            int gn = col0 + wn*64 + j*16 + fr;
            if (gn >= Nd) continue;
            float b1 = bias1 ? bias1[gn] : 0.f;
            #pragma unroll
            for (int r = 0; r < 4; r++){
                int gm = gmb + r;
                if (gm >= Md) continue;
                float v = acc[i][j][r] + b1;
                if (doGelu) v = gelu_exact(v);
                C[(long)gm*ldC + gn] = (bf16_t)v;
            }
        }
    }
}

// ---------------- MFMA bf16 GEMM: 128x128 tile, BK=32, 4 waves ----------------
// mode 0: f32 rowmajor (+Cadd, LN partials); mode 1: bf16 rowmajor;
// mode 7: split-K over z (2 halves) -> raw fp32 partial buffers.
__global__ void __launch_bounds__(256)
mfma_gemm_k(const bf16_t* __restrict__ A, long ldA, long sA,
            const bf16_t* __restrict__ B, long ldB, long sB,
            void* __restrict__ C, long ldC, long sC,
            const float* __restrict__ Cadd,
            const float* __restrict__ bias1,
            const float* __restrict__ bias2, int b2mod, int b2ld,
            int Md, int Nd, int Kd, float alpha, int doGelu, int mode,
            float* __restrict__ psum, float* __restrict__ psq, int redN, int G)
{
    __shared__ bf16_t sm[3][2][128][32];   // 48 KiB triple-buffered
    __shared__ float redbuf[8];
    const int tid = threadIdx.x;
    const int lane = tid & 63, w = tid >> 6;
    const int wm = w >> 1, wn = w & 1;
    const int z = blockIdx.z;

    long kStart = 0; int KdL = Kd; long zA = z;
    if (mode == 7){ kStart = (long)z * (Kd >> 1); KdL = Kd >> 1; zA = 0; }

    int n2d = gridDim.x * gridDim.y;
    int flat = blockIdx.x + gridDim.x * blockIdx.y;
    int q8 = n2d >> 3, r8 = n2d & 7;
    int xcd = flat & 7, pos = flat >> 3;
    int lid = (xcd < r8 ? xcd*(q8+1) : r8*(q8+1) + (xcd-r8)*q8) + pos;
    int gx = gridDim.x, gy = gridDim.y;
    int fullg = gx / G;
    int fullsz = fullg * G * gy;
    int bx, by;
    if (lid < fullsz){
        int gsz = G * gy;
        int g = lid / gsz, rem = lid - g*gsz;
        by = rem / G; bx = g*G + (rem - by*G);
    } else {
        int tw = gx - fullg*G;
        int rem = lid - fullsz;
        by = rem / tw; bx = fullg*G + (rem - by*tw);
    }

    const int row0 = by * 128, col0 = bx * 128;

    const bf16_t* Ab = A + zA * sA + (long)row0 * ldA + kStart;
    const bf16_t* Bb = B + zA * sB + (long)col0 * ldB + kStart;

    f32x4 acc[4][4];
    #pragma unroll
    for (int i = 0; i < 4; i++)
        #pragma unroll
        for (int j = 0; j < 4; j++)
            acc[i][j] = (f32x4){0.f, 0.f, 0.f, 0.f};

    const int fr = lane & 15, kc = lane >> 4;
    const int swz = (fr >> 1) & 3;
    int aOff[4], bOff[4];
    #pragma unroll
    for (int i = 0; i < 4; i++){
        aOff[i] = (wm*64 + i*16 + fr) * 64 + ((kc ^ swz) << 4);
        bOff[i] = (wn*64 + i*16 + fr) * 64 + ((kc ^ swz) << 4);
    }

    auto stage = [&](int buf, int kt){
        long kOff = (long)kt * 32;
        #pragma unroll
        for (int r = 0; r < 2; r++){
            int idx = r*256 + tid;
            int row = idx >> 2, cp = idx & 3;
            int cc = cp ^ ((row >> 1) & 3);
            gld16((const void*)(Ab + (long)row*ldA + kOff + cc*8), (void*)&sm[buf][0][row][cp*8]);
            gld16((const void*)(Bb + (long)row*ldB + kOff + cc*8), (void*)&sm[buf][1][row][cp*8]);
        }
    };

    const int nt = KdL >> 5;
    stage(0, 0);
    stage(1, 1);
    asm volatile("s_waitcnt vmcnt(4)" ::: "memory");
    __builtin_amdgcn_s_barrier();
    __builtin_amdgcn_sched_barrier(0);

    for (int t = 0; t < nt; t++){
        int cur = t % 3;
        if (t + 2 < nt) stage((t + 2) % 3, t + 2);
        const char* baseA = (const char*)sm + cur * 16384;
        const char* baseB = baseA + 8192;
        bf16x8 av[4], bv[4];
        #pragma unroll
        for (int i = 0; i < 4; i++){
            av[i] = *(const bf16x8*)(baseA + aOff[i]);
            bv[i] = *(const bf16x8*)(baseB + bOff[i]);
        }
        __builtin_amdgcn_s_setprio(1);
        #pragma unroll
        for (int i = 0; i < 4; i++)
            #pragma unroll
            for (int j = 0; j < 4; j++)
                acc[i][j] = __builtin_amdgcn_mfma_f32_16x16x32_bf16(av[i], bv[j], acc[i][j], 0, 0, 0);
        __builtin_amdgcn_s_setprio(0);
        if (t + 2 < nt)      asm volatile("s_waitcnt vmcnt(4)" ::: "memory");
        else if (t + 1 < nt) asm volatile("s_waitcnt vmcnt(0)" ::: "memory");
        __builtin_amdgcn_s_barrier();
        __builtin_amdgcn_sched_barrier(0);
    }

    float rs = 0.f, rq = 0.f;
    #pragma unroll
    for (int i = 0; i < 4; i++){
        int gmb = row0 + wm*64 + i*16 + kc*4;
        #pragma unroll
        for (int j = 0; j < 4; j++){
            int gn = col0 + wn*64 + j*16 + fr;
            if (gn >= Nd) continue;
            #pragma unroll
            for (int r = 0; r < 4; r++){
                int gm = gmb + r;
                if (gm >= Md) continue;
                float v = alpha * acc[i][j][r];
                if (bias1) v += bias1[gn];
                if (bias2) v += bias2[(long)(gm % b2mod) * b2ld + gn];
                if (doGelu) v = gelu_exact(v);
                if (mode == 0){
                    long off = (long)z*sC + (long)gm*ldC + gn;
                    if (Cadd) v += Cadd[off];
                    ((float*)C)[off] = v;
                    rs += v; rq += v*v;
                } else if (mode == 7){
                    ((float*)C)[(long)z*sC + (long)gm*ldC + gn] = v;
                } else {
                    ((bf16_t*)C)[(long)z*sC + (long)gm*ldC + gn] = (bf16_t)v;
                }
            }
        }
    }

    if (redN > 0){
        #pragma unroll
        for (int off = 32; off > 0; off >>= 1){
            rs += __shfl_xor(rs, off); rq += __shfl_xor(rq, off);
        }
        if (lane == 0){ redbuf[w] = rs; redbuf[4 + w] = rq; }
        __syncthreads();
        if (tid == 0){
            psum[flat] = redbuf[0] + redbuf[1] + redbuf[2] + redbuf[3];
            psq[flat]  = redbuf[4] + redbuf[5] + redbuf[6] + redbuf[7];
        }
    }
}

// ---------------- 64x64-tile MFMA GEMM, BK=64 (t-projection) ------
__global__ void __launch_bounds__(256)
gemm64_k(const bf16_t* __restrict__ A, long ldA, long sA,
         const bf16_t* __restrict__ B, long ldB, long sB,
         bf16_t* __restrict__ C, long ldC, long sC,
         const float* __restrict__ bias2, int b2ld,
         int Md, int Nd, int Kd)
{
    __shared__ bf16_t sm[3][2][64][64];   // 48 KiB triple-buffered, BK=64
    const int tid = threadIdx.x;
    const int lane = tid & 63, w = tid >> 6;
    const int wm = w >> 1, wn = w & 1;
    const int z = blockIdx.z;
    const int row0 = blockIdx.y * 64, col0 = blockIdx.x * 64;

    const bf16_t* Ab = A + (long)z * sA + (long)row0 * ldA;
    const bf16_t* Bb = B + (long)z * sB + (long)col0 * ldB;

    f32x4 acc[2][2];
    #pragma unroll
    for (int i = 0; i < 2; i++)
        #pragma unroll
        for (int j = 0; j < 2; j++)
            acc[i][j] = (f32x4){0.f,0.f,0.f,0.f};

    const int fr = lane & 15, kc = lane >> 4;
    int aOff[2][2], bOff[2][2];
    #pragma unroll
    for (int i = 0; i < 2; i++){
        int rowa = wm*32 + i*16 + fr;
        int rowb = wn*32 + i*16 + fr;
        #pragma unroll
        for (int s = 0; s < 2; s++){
            aOff[i][s] = rowa*128 + ((((s<<2)|kc) ^ (rowa & 7)) << 4);
            bOff[i][s] = rowb*128 + ((((s<<2)|kc) ^ (rowb & 7)) << 4);
        }
    }

    auto stage = [&](int buf, int kt){
        long kOff = (long)kt * 64;
        #pragma unroll
        for (int r = 0; r < 2; r++){
            int idx = r*256 + tid;
            int row = idx >> 3, cp = idx & 7;
            int cc = cp ^ (row & 7);
            gld16((const void*)(Ab + (long)row*ldA + kOff + cc*8), (void*)&sm[buf][0][row][cp*8]);
            gld16((const void*)(Bb + (long)row*ldB + kOff + cc*8), (void*)&sm[buf][1][row][cp*8]);
        }
    };

    const int nt = Kd >> 6;    // BK=64
    stage(0, 0);
    stage(1, 1);
    asm volatile("s_waitcnt vmcnt(4)" ::: "memory");
    __builtin_amdgcn_s_barrier();
    __builtin_amdgcn_sched_barrier(0);

    for (int t = 0; t < nt; t++){
        int cur = t % 3;
        if (t + 2 < nt) stage((t + 2) % 3, t + 2);
        const char* baseA = (const char*)sm + cur * 16384;
        const char* baseB = baseA + 8192;
        __builtin_amdgcn_s_setprio(1);
        #pragma unroll
        for (int s = 0; s < 2; s++){
            bf16x8 av0 = *(const bf16x8*)(baseA + aOff[0][s]);
            bf16x8 av1 = *(const bf16x8*)(baseA + aOff[1][s]);
            bf16x8 bv0 = *(const bf16x8*)(baseB + bOff[0][s]);
            bf16x8 bv1 = *(const bf16x8*)(baseB + bOff[1][s]);
            acc[0][0] = __builtin_amdgcn_mfma_f32_16x16x32_bf16(av0, bv0, acc[0][0], 0, 0, 0);
            acc[0][1] = __builtin_amdgcn_mfma_f32_16x16x32_bf16(av0, bv1, acc[0][1], 0, 0, 0);
            acc[1][0] = __builtin_amdgcn_mfma_f32_16x16x32_bf16(av1, bv0, acc[1][0], 0, 0, 0);
            acc[1][1] = __builtin_amdgcn_mfma_f32_16x16x32_bf16(av1, bv1, acc[1][1], 0, 0, 0);
        }
        __builtin_amdgcn_s_setprio(0);
        if (t + 2 < nt)      asm volatile("s_waitcnt vmcnt(4)" ::: "memory");
        else if (t + 1 < nt) asm volatile("s_waitcnt vmcnt(0)" ::: "memory");
        __builtin_amdgcn_s_barrier();
        __builtin_amdgcn_sched_barrier(0);
    }

    #pragma unroll
    for (int i = 0; i < 2; i++){
        int gmb = row0 + wm*32 + i*16 + kc*4;
        #pragma unroll
        for (int j = 0; j < 2; j++){
            int gn = col0 + wn*32 + j*16 + fr;
            if (gn >= Nd) continue;
            #pragma unroll
            for (int r = 0; r < 4; r++){
                int gm = gmb + r;
                if (gm >= Md) continue;
                float v = acc[i][j][r];
                if (bias2) v += bias2[(long)gm * b2ld + gn];
                C[(long)z*sC + (long)gm*ldC + gn] = (bf16_t)v;
            }
        }
    }
}

// ---------------- head: [32 x 150528] @ [150528 x 512] fp32, split-K ----------------
__global__ void __launch_bounds__(256)
head_splitk_k(const float* __restrict__ A, const float* __restrict__ W, float* __restrict__ feat)
{
    __shared__ float As[16][36];
    __shared__ float Bs[16][68];
    int col0 = blockIdx.x * 64;
    long kbase = (long)blockIdx.y * 2352;
    int tid = threadIdx.x, tx = tid & 15, ty = tid >> 4;
    float acc[2][4] = {};
    for (int k0 = 0; k0 < 2352; k0 += 16){
        #pragma unroll
        for (int u = 0; u < 2; u++){
            int idx = tid * 2 + u;
            int m = idx >> 4, kk = idx & 15;
            As[kk][m] = A[(long)m * KHEAD + kbase + k0 + kk];
        }
        #pragma unroll
        for (int u = 0; u < 4; u++){
            int idx = tid * 4 + u;
            int kk = idx >> 6, n = idx & 63;
            Bs[kk][n] = W[(kbase + k0 + kk) * 512 + col0 + n];
        }
        __syncthreads();
        #pragma unroll
        for (int kk = 0; kk < 16; kk++){
            float a0 = As[kk][ty*2], a1 = As[kk][ty*2+1];
            float b0 = Bs[kk][tx*4], b1 = Bs[kk][tx*4+1], b2 = Bs[kk][tx*4+2], b3 = Bs[kk][tx*4+3];
            acc[0][0] += a0*b0; acc[0][1] += a0*b1; acc[0][2] += a0*b2; acc[0][3] += a0*b3;
            acc[1][0] += a1*b0; acc[1][1] += a1*b1; acc[1][2] += a1*b2; acc[1][3] += a1*b3;
        }
        __syncthreads();
    }
    #pragma unroll
    for (int i = 0; i < 2; i++)
        #pragma unroll
        for (int j = 0; j < 4; j++)
            atomicAdd(&feat[(ty*2 + i) * 512 + col0 + tx*4 + j], acc[i][j]);
}

// cls with fused gelu(feat + head_b)
__global__ void __launch_bounds__(256)
cls_k(const float* __restrict__ feat, const float* __restrict__ hb,
      const float* __restrict__ W, const float* __restrict__ bias, float* __restrict__ out)
{
    __shared__ float fs[512];
    int b = blockIdx.y;
    int j = blockIdx.x * 256 + threadIdx.x;
    for (int i = threadIdx.x; i < 512; i += 256)
        fs[i] = gelu_exact(feat[b * 512 + i] + hb[i]);
    __syncthreads();
    if (j < NCLS){
        float s = bias[j];
        for (int k = 0; k < 512; k++) s += fs[k] * W[(long)k * NCLS + j];
        out[b * NCLS + j] = s;
    }
}

// ---------------- launch ----------------
extern "C" void kernel_launch(void* const* d_in, const int* in_sizes, int n_in,
                              void* d_out, int out_size, void* d_ws, size_t ws_size,
                              hipStream_t stream)
{
    const float* image   = (const float*)d_in[0];
    const float* patch_w = (const float*)d_in[1];
    const float* patch_b = (const float*)d_in[2];
    const float* pos_emb = (const float*)d_in[3];
    const float* qw  = (const float*)d_in[4];
    const float* qb  = (const float*)d_in[5];
    const float* kw  = (const float*)d_in[6];
    const float* kb  = (const float*)d_in[7];
    const float* vw  = (const float*)d_in[8];
    const float* vb  = (const float*)d_in[9];
    const float* ow1 = (const float*)d_in[10];
    const float* ob1 = (const float*)d_in[11];
    const float* ow2 = (const float*)d_in[12];
    const float* ob2 = (const float*)d_in[13];
    const float* d1w = (const float*)d_in[14];
    const float* d1b = (const float*)d_in[15];
    const float* d2w = (const float*)d_in[16];
    const float* d2b = (const float*)d_in[17];
    const float* head_w = (const float*)d_in[18];
    const float* head_b = (const float*)d_in[19];
    const float* cls_w  = (const float*)d_in[20];
    const float* cls_b  = (const float*)d_in[21];

    char* wsb = (char*)d_ws;
    float*  X    = (float*) (wsb + OB_X);
    float*  R    = (float*) (wsb + OB_R);
    bf16_t* XB   = (bf16_t*)(wsb + OB_XB);
    bf16_t* XQKV = (bf16_t*)(wsb + OB_XQKV);
    float*  P0   = (float*) (wsb + OB_P0);
    bf16_t* O    = (bf16_t*)(wsb + OB_O);
    bf16_t* Tt   = (bf16_t*)(wsb + OB_T);
    bf16_t* H1   = XQKV;
    bf16_t* PATB = XQKV;
    bf16_t* WQKV = (bf16_t*)(wsb + OB_WQKV);
    bf16_t* WO1  = (bf16_t*)(wsb + OB_WO1);
    bf16_t* WO2  = (bf16_t*)(wsb + OB_WO2);
    bf16_t* WD1  = (bf16_t*)(wsb + OB_WD1);
    bf16_t* WD2  = (bf16_t*)(wsb + OB_WD2);
    bf16_t* WPAT = (bf16_t*)(wsb + OB_WPAT);
    float*  BQKV = (float*) (wsb + OB_BQKV);
    float*  OB1T = (float*) (wsb + OB_OB1T);
    float*  PS   = (float*) (wsb + OB_RED);
    float*  PQ   = PS + NPARTF;
    float*  FEAT = (float*) (wsb + OB_FEAT);
    float*  out  = (float*)d_out;

    hipFuncSetAttribute((const void*)attn_fused_k,
                        hipFuncAttributeMaxDynamicSharedMemorySize, ATTN_LDS);
    hipFuncSetAttribute((const void*)gemm256_k,
                        hipFuncAttributeMaxDynamicSharedMemorySize, G256_LDS);

    auto pickG = [](int Kd){
        int g = (3*1024*1024) / (128 * Kd * 2);
        if (g > 8) g = 8;
        if (g < 1) g = 1;
        return g;
    };
    auto mg = [&](const bf16_t* A, long ldA, long sA, const bf16_t* B, long ldB, long sB,
                  void* C, long ldC, long sC, const float* Cadd, const float* b1,
                  const float* b2, int b2mod, int b2ld,
                  int Md, int Nd, int Kd, int nb, float alpha, int gelu, int mode, int redN){
        dim3 g((Nd + 127) / 128, (Md + 127) / 128, nb);
        mfma_gemm_k<<<g, 256, 0, stream>>>(A, ldA, sA, B, ldB, sB, C, ldC, sC,
                                           Cadd, b1, b2, b2mod, b2ld,
                                           Md, Nd, Kd, alpha, gelu, mode, PS, PQ, redN,
                                           pickG(Kd));
    };
    auto wconv = [&](const float* in, bf16_t* o_, int IR, int IC, int perm, long OLD,
                     int padTo, int nz, long inZ, long outZ){
        dim3 g((IC + 31) / 32, (padTo + 31) / 32, nz);
        wconv_k<<<g, 256, 0, stream>>>(in, o_, IR, IC, OLD, perm, padTo, inZ, outZ);
    };
    auto lnapply = [&](const float* in, bf16_t* ob, float* of, int npart){
        ln_apply_k<<<4704, 256, 0, stream>>>(in, ob, of, PS, PQ, npart);
    };

    // ---- bulk weight conversion (all layers upfront) ----
    wconv(patch_w, WPAT, 768, 768, 0, 768, 768, 1, 0, 0);
    wconv(qw, WQKV,               768, 2304, 1, 768, 768, 6, 768L*2304, 6912L*768);
    wconv(kw, WQKV + 2304L*768,   768, 2304, 1, 768, 768, 6, 768L*2304, 6912L*768);
    wconv(vw, WQKV + 4608L*768,   768, 2304, 1, 768, 768, 6, 768L*2304, 6912L*768);
    wconv(ow1, WO1, 2352, 196, 0, 2368, 2368, 6, 2352L*196, 606208L);
    wconv(ow2, WO2, 192, 768, 0, 192, 192, 6, 147456L, 147456L);
    wconv(d1w, WD1, 768, 3072, 0, 768, 768, 6, 2359296L, 2359296L);
    wconv(d2w, WD2, 3072, 768, 0, 3072, 3072, 6, 2359296L, 2359296L);
    gather_bias_k<<<dim3(27, 6), 256, 0, stream>>>(qb, kb, vb, BQKV);
    tr_bias_k<<<dim3(147, 6), 256, 0, stream>>>(ob1, OB1T);

    // ---- patch encode (writes X + LN partials, grid 294) ----
    patch_extract_k<<<18816, 256, 0, stream>>>(image, PATB);
    mg(PATB, 768, 0, WPAT, 768, 0, X, 768, 0,
       nullptr, patch_b, pos_emb, 196, 768, 6272, 768, 768, 1, 1.f, 0, 0, NPART);
    zero_pad_o_k<<<384, 256, 0, stream>>>(O);

    for (int l = 0; l < NLAY; l++){
        lnapply(X, XB, nullptr, l == 0 ? NPART : NPARTF);            // x1
        // QKV: 256x256-tile kernel, row-major [6272][6912]
        gemm256_k<<<dim3(27, 25), 512, G256_LDS, stream>>>(
            XB, 768, WQKV + (long)l*6912*768, 768, XQKV, 6912,
            BQKV + l*6912, 6272, 6912, 768, 8, 0);
        // fused attention (builds V^T in-kernel) -> O
        attn_fused_k<<<dim3(2, 384), 256, ATTN_LDS, stream>>>(XQKV, O);
        // t[b][n][m] = ow1^T_n . o_b_m + ob1^T  (64x64 tiles, BK=64, 384 blocks)
        gemm64_k<<<dim3(3, 4, 32), 256, 0, stream>>>(
            WO1 + (long)l*606208, 2368, 0, O, 2368, 192L*2368, Tt, 192, 37632,
            OB1T + (long)l*37632, 192, 196, 192, 2368);
        // x2 = t @ ow2 + ob2 + X -> R  (grid 294, LN partials)
        mg(Tt, 192, 0, WO2 + (long)l*147456, 192, 0, R, 768, 0, X, nullptr,
           ob2 + (long)l*196*768, 196, 768, 6272, 768, 192, 1, 1.f, 0, 0, NPART);
        lnapply(R, XB, nullptr, NPART);                              // x3
        // FFN1: 128x128 tiles (1176 blocks), gelu fused
        mg(XB, 768, 0, WD1 + (long)l*2359296, 768, 0, H1, 3072, 0, nullptr,
           d1b + l*3072, nullptr, 1, 1, 6272, 3072, 768, 1, 1.f, 1, 1, 0);
        // FFN2 split-K=2 -> fp32 partials (588 blocks), then fused finish
        mg(H1, 3072, 0, WD2 + (long)l*2359296, 3072, 0, P0, 768, 4816896, nullptr,
           nullptr, nullptr, 1, 1, 6272, 768, 3072, 2, 1.f, 0, 7, 0);
        ffn2_finish_k<<<4704, 256, 0, stream>>>(P0, R, d2b + l*768, X, PS, PQ);
    }

    lnapply(X, XB, R, NPARTF);                                       // final LN -> R fp32
    hipMemsetAsync(FEAT, 0, BZ * HEADU * sizeof(float), stream);
    head_splitk_k<<<dim3(8, 64), 256, 0, stream>>>(R, head_w, FEAT);
    cls_k<<<dim3(4, 32), 256, 0, stream>>>(FEAT, head_b, cls_w, cls_b, out);
    (void)in_sizes; (void)n_in; (void)out_size; (void)ws_size;
}

// Round 13
// 3126.088 us; speedup vs baseline: 1.0083x; 1.0083x over previous
//
#include <hip/hip_runtime.h>
#include <cmath>

// ---------------- problem constants ----------------
#define BZ    32
#define NP    196
#define DDIM  768
#define NHEAD 12
#define MDIM  192
#define NLAY  6
#define FFDIM 3072
#define HEADU 512
#define NCLS  1000
#define KHEAD 150528      // NP*DDIM
#define BND   4816896     // BZ*NP*DDIM
#define NPART 294         // partial-stat slots for 294-block GEMM producers
#define NPARTF 4704       // partial-stat slots for ffn2_finish producer

typedef __bf16 bf16_t;
typedef __bf16 bf16x8 __attribute__((ext_vector_type(8)));
typedef __bf16 bf16x4 __attribute__((ext_vector_type(4)));
typedef float  f32x4  __attribute__((ext_vector_type(4)));
typedef float  f32x2  __attribute__((ext_vector_type(2)));

// ---------------- workspace layout (BYTE offsets) ----------------
#define OB_X      0L
#define OB_R      19267584L
#define OB_XB     38535168L
#define OB_XQKV   48168960L     // [6272][6912] bf16; first 38.5MB aliases H1/PATB
#define OB_P0     86704128L     // fp32 FFN2 partials, 2 x 19,267,584 (inside XQKV slack)
#define OB_VT     134873088L
#define OB_O      165543936L
#define OB_T      194641920L
#define OB_WQKV   197050368L
#define OB_WO1    260751360L
#define OB_WO2    268025856L
#define OB_WD1    269795328L
#define OB_WD2    298106880L
#define OB_WPAT   326418432L
#define OB_BQKV   327598080L
#define OB_OB1T   327763968L
#define OB_RED    328667136L    // 2 x 4704 fp32
#define OB_FEAT   328704768L

#define VT_SSTRIDE  39936L
#define ATTN_LDSP   93184
#define ATTN_LDS    143360
#define G256_LDS    98304
#define XROW        13824

__device__ __forceinline__ float gelu_exact(float x){
    return 0.5f * x * (1.0f + erff(x * 0.70710678118654752f));
}

__device__ __forceinline__ void gld16(const void* g, void* l){
    __builtin_amdgcn_global_load_lds((const __attribute__((address_space(1))) void*)g,
                                     (__attribute__((address_space(3))) void*)l, 16, 0, 0);
}

// ---------------- patch extraction (fp32 -> bf16) ----------------
__global__ void __launch_bounds__(256)
patch_extract_k(const float* __restrict__ img, bf16_t* __restrict__ out)
{
    long idx = (long)blockIdx.x * 256 + threadIdx.x;
    if (idx >= (long)BND) return;
    int k = (int)(idx % DDIM);
    long bn = idx / DDIM;
    int n = (int)(bn % NP);
    int b = (int)(bn / NP);
    int c  = k % 3;
    int pj = (k / 3) % 16;
    int pi = k / 48;
    int gi = n / 14, gj = n % 14;
    long src = (((long)(b * 224 + gi * 16 + pi)) * 224 + (gj * 16 + pj)) * 3 + c;
    out[idx] = (bf16_t)img[src];
}

// ---------------- weight convert+transpose fp32->bf16 (layer-batched) --------
__global__ void __launch_bounds__(256)
wconv_k(const float* __restrict__ in, bf16_t* __restrict__ out,
        int IR, int IC, long OLD, int perm, int padTo, long inZ, long outZ)
{
    __shared__ float tile[32][33];
    int tid = threadIdx.x, tx = tid & 31, ty = tid >> 5;
    int c0 = blockIdx.x * 32, r0 = blockIdx.y * 32;
    const float* inz = in + (long)blockIdx.z * inZ;
    bf16_t* outz = out + (long)blockIdx.z * outZ;
    #pragma unroll
    for (int i = 0; i < 4; i++){
        int r = r0 + ty + 8*i, c = c0 + tx;
        tile[ty + 8*i][tx] = (r < IR && c < IC) ? inz[(long)r * IC + c] : 0.f;
    }
    __syncthreads();
    #pragma unroll
    for (int i = 0; i < 4; i++){
        int c = c0 + ty + 8*i, r = r0 + tx;
        if (c < IC && r < padTo){
            long pc = perm ? (long)(c % 12) * 192 + c / 12 : (long)c;
            outz[pc * OLD + r] = (bf16_t)tile[tx][ty + 8*i];
        }
    }
}

// ---------------- gather QKV bias into [6][6912] ----------------
__global__ void __launch_bounds__(256)
gather_bias_k(const float* __restrict__ qb, const float* __restrict__ kb,
              const float* __restrict__ vb, float* __restrict__ out)
{
    int tid = blockIdx.x * 256 + threadIdx.x;
    int l = blockIdx.y;
    if (tid >= 6912) return;
    int g = tid / 2304, w = tid % 2304;
    int h = w / 192, m = w % 192;
    const float* src = (g == 0) ? qb : (g == 1) ? kb : vb;
    out[l*6912 + tid] = src[l*2304 + m * 12 + h];
}

// ---------------- transpose ob1 [6][192][196] -> [6][196][192] fp32 ----------
__global__ void __launch_bounds__(256)
tr_bias_k(const float* __restrict__ ob1, float* __restrict__ out)
{
    int idx = blockIdx.x * 256 + threadIdx.x;
    int l = blockIdx.y;
    if (idx >= 37632) return;
    int n = idx / 192, m = idx - n*192;
    out[(long)l*37632 + idx] = ob1[(long)l*37632 + m*196 + n];
}

// ---------------- zero O pad columns [2352,2368) ----------------
__global__ void __launch_bounds__(256)
zero_pad_o_k(bf16_t* __restrict__ o)
{
    int idx = blockIdx.x * 256 + threadIdx.x;
    if (idx >= 6144*16) return;
    int r = idx >> 4, j = idx & 15;
    o[(long)r * 2368 + 2352 + j] = (bf16_t)0.f;
}

// ---------------- V transpose: XQKV V-block -> VT [slab][192][208] (pad 0) ----
__global__ void __launch_bounds__(256)
tr_v_k(const bf16_t* __restrict__ X, bf16_t* __restrict__ VT)
{
    __shared__ bf16_t tile[32][33];
    int tid = threadIdx.x, tx = tid & 31, ty = tid >> 5;
    int s = blockIdx.z, b = s & 31, h = s >> 5;
    int m0 = blockIdx.x * 32, n0 = blockIdx.y * 32;
    #pragma unroll
    for (int i = 0; i < 4; i++){
        int r = n0 + ty + 8*i, c = m0 + tx;
        tile[ty + 8*i][tx] = (r < 196) ?
            X[(long)(b*196 + r) * 6912 + 4608 + h*192 + c] : (bf16_t)0.f;
    }
    __syncthreads();
    #pragma unroll
    for (int i = 0; i < 4; i++){
        int m = m0 + ty + 8*i, n = n0 + tx;
        if (n < 208)
            VT[(long)s * VT_SSTRIDE + (long)m * 208 + n] = tile[tx][ty + 8*i];
    }
}

// ---------------- global layernorm apply (reduces npart partials inline) -----
__global__ void __launch_bounds__(256)
ln_apply_k(const float* __restrict__ x, bf16_t* __restrict__ yb, float* __restrict__ yf,
           const float* __restrict__ psum, const float* __restrict__ psq, int npart)
{
    __shared__ float sred[8];
    int tid = threadIdx.x;
    float s = 0.f, q = 0.f;
    for (int i = tid; i < npart; i += 256){ s += psum[i]; q += psq[i]; }
    #pragma unroll
    for (int off = 32; off > 0; off >>= 1){ s += __shfl_xor(s, off); q += __shfl_xor(q, off); }
    if ((tid & 63) == 0){ sred[(tid>>6)*2] = s; sred[(tid>>6)*2+1] = q; }
    __syncthreads();
    s = sred[0] + sred[2] + sred[4] + sred[6];
    q = sred[1] + sred[3] + sred[5] + sred[7];
    float mean = s / (float)BND;
    float inv  = rsqrtf(q / (float)BND - mean*mean + 1e-6f);

    long i = (long)blockIdx.x * 256 + tid;
    if (i >= BND / 4) return;
    float4 v = ((const float4*)x)[i];
    v.x = (v.x - mean) * inv;
    v.y = (v.y - mean) * inv;
    v.z = (v.z - mean) * inv;
    v.w = (v.w - mean) * inv;
    bf16x4 o4 = { (bf16_t)v.x, (bf16_t)v.y, (bf16_t)v.z, (bf16_t)v.w };
    ((bf16x4*)yb)[i] = o4;
    if (yf) ((float4*)yf)[i] = v;
}

// ---------------- FFN2 finish: X = gelu(P0+P1+d2b) + R, + LN partials -------
__global__ void __launch_bounds__(256)
ffn2_finish_k(const float* __restrict__ P, const float* __restrict__ R,
              const float* __restrict__ d2b, float* __restrict__ X,
              float* __restrict__ psum, float* __restrict__ psq)
{
    __shared__ float redbuf[8];
    int tid = threadIdx.x;
    long i = (long)blockIdx.x * 256 + tid;    // f32x4 index; grid covers BND/4 exactly
    float4 a = ((const float4*)P)[i];
    float4 b = ((const float4*)(P + 4816896))[i];
    float4 r = ((const float4*)R)[i];
    int col = (int)((i * 4) % 768);
    float v0 = gelu_exact(a.x + b.x + d2b[col])     + r.x;
    float v1 = gelu_exact(a.y + b.y + d2b[col + 1]) + r.y;
    float v2 = gelu_exact(a.z + b.z + d2b[col + 2]) + r.z;
    float v3 = gelu_exact(a.w + b.w + d2b[col + 3]) + r.w;
    float4 o; o.x = v0; o.y = v1; o.z = v2; o.w = v3;
    ((float4*)X)[i] = o;
    float rs = v0 + v1 + v2 + v3;
    float rq = v0*v0 + v1*v1 + v2*v2 + v3*v3;
    #pragma unroll
    for (int off = 32; off > 0; off >>= 1){ rs += __shfl_xor(rs, off); rq += __shfl_xor(rq, off); }
    if ((tid & 63) == 0){ redbuf[(tid>>6)*2] = rs; redbuf[(tid>>6)*2+1] = rq; }
    __syncthreads();
    if (tid == 0){
        psum[blockIdx.x] = redbuf[0] + redbuf[2] + redbuf[4] + redbuf[6];
        psq[blockIdx.x]  = redbuf[1] + redbuf[3] + redbuf[5] + redbuf[7];
    }
}

// ---------------- fused attention ----------------
__global__ void __launch_bounds__(256)
attn_fused_k(const bf16_t* __restrict__ XQKV, const bf16_t* __restrict__ VT,
             bf16_t* __restrict__ O)
{
    extern __shared__ char lds[];
    const int tid = threadIdx.x, lane = tid & 63, w = tid >> 6;
    const int fr = lane & 15, kc = lane >> 4;
    const int s = blockIdx.y, qhalf = blockIdx.x;
    const int q0 = qhalf * 112;
    const int b = s & 31, h = s >> 5;
    const float scale = 0.03608439182435161f;   // 1/sqrt(768)
    const char* Xb = (const char*)XQKV + (long)(b*196) * XROW;
    const char* Qs = Xb + h*384;
    const char* Ks = Xb + 4608 + h*384;
    const char* Vs = (const char*)(VT + (long)s * VT_SSTRIDE);

    for (int t = 0; t < 23; t++){
        int idx = t*256 + tid;
        if (idx < 5824){
            int row = idx / 28, sl = idx - row*28;
            bool val = (sl < 24) && (row < 196);
            const char* src = Ks + (val ? ((long)row*XROW + ((sl*16) ^ ((row & 7) << 4))) : 0);
            gld16(src, lds + idx*16);
        }
    }
    asm volatile("s_waitcnt vmcnt(0)");
    __syncthreads();

    float pv_all[2][13][4];
    #pragma unroll
    for (int ii = 0; ii < 2; ii++){
        int i = w + ii*4;
        if (i >= 7) continue;
        f32x4 sa[13];
        #pragma unroll
        for (int f = 0; f < 13; f++) sa[f] = (f32x4){0.f,0.f,0.f,0.f};
        int qr = q0 + i*16 + fr; if (qr > 195) qr = 195;
        #pragma unroll
        for (int c = 0; c < 6; c++){
            bf16x8 av = *(const bf16x8*)(Qs + (long)qr*XROW + c*64 + kc*16);
            #pragma unroll
            for (int f = 0; f < 13; f++){
                int krow = f*16 + fr;
                bf16x8 bv = *(const bf16x8*)(lds + krow*448 + ((c*64 + kc*16) ^ ((krow & 7) << 4)));
                sa[f] = __builtin_amdgcn_mfma_f32_16x16x32_bf16(av, bv, sa[f], 0, 0, 0);
            }
        }
        #pragma unroll
        for (int r = 0; r < 4; r++){
            float mx = -1e30f;
            #pragma unroll
            for (int f = 0; f < 13; f++)
                if (f*16 + fr < 196) mx = fmaxf(mx, sa[f][r] * scale);
            mx = fmaxf(mx, __shfl_xor(mx, 1));
            mx = fmaxf(mx, __shfl_xor(mx, 2));
            mx = fmaxf(mx, __shfl_xor(mx, 4));
            mx = fmaxf(mx, __shfl_xor(mx, 8));
            float sum = 0.f;
            #pragma unroll
            for (int f = 0; f < 13; f++){
                float pv = (f*16 + fr < 196) ? __expf(sa[f][r] * scale - mx) : 0.f;
                pv_all[ii][f][r] = pv; sum += pv;
            }
            sum += __shfl_xor(sum, 1);
            sum += __shfl_xor(sum, 2);
            sum += __shfl_xor(sum, 4);
            sum += __shfl_xor(sum, 8);
            float inv = 1.f / sum;
            #pragma unroll
            for (int f = 0; f < 13; f++) pv_all[ii][f][r] *= inv;
        }
        #pragma unroll
        for (int f = 0; f < 13; f++)
            #pragma unroll
            for (int r = 0; r < 4; r++){
                int row = i*16 + kc*4 + r;
                int cb = (f*16 + fr) * 2;
                int a = ATTN_LDSP + row*448 + (cb < 384 ? (cb ^ ((row & 7) << 4)) : cb);
                *(bf16_t*)(lds + a) = (bf16_t)pv_all[ii][f][r];
            }
        if (lane < 32){
            int row = i*16 + (lane >> 1);
            *(f32x4*)(lds + ATTN_LDSP + row*448 + 416 + (lane & 1)*16) = (f32x4){0.f,0.f,0.f,0.f};
        }
    }
    __syncthreads();

    for (int t = 0; t < 21; t++){
        int idx = t*256 + tid;
        int row = idx / 28, sl = idx - row*28;
        bool val = (sl < 26);
        int cb = (sl < 24) ? ((sl*16) ^ ((row & 7) << 4)) : sl*16;
        const char* src = Vs + (val ? (row*416 + cb) : 0);
        gld16(src, lds + idx*16);
    }
    asm volatile("s_waitcnt vmcnt(0)");
    __syncthreads();

    f32x4 oa2[2][12];
    #pragma unroll
    for (int ii = 0; ii < 2; ii++){
        int i = w + ii*4;
        #pragma unroll
        for (int f = 0; f < 12; f++) oa2[ii][f] = (f32x4){0.f,0.f,0.f,0.f};
        if (i >= 7) continue;
        #pragma unroll
        for (int c = 0; c < 7; c++){
            int prow = i*16 + fr;
            int cb = c*64 + kc*16;
            int acb = (cb < 384) ? (cb ^ ((prow & 7) << 4)) : cb;
            bf16x8 av = *(const bf16x8*)(lds + ATTN_LDSP + prow*448 + acb);
            #pragma unroll
            for (int f = 0; f < 12; f++){
                int vrow = f*16 + fr;
                int bcb = (cb < 384) ? (cb ^ ((vrow & 7) << 4)) : cb;
                bf16x8 bv = *(const bf16x8*)(lds + vrow*448 + bcb);
                oa2[ii][f] = __builtin_amdgcn_mfma_f32_16x16x32_bf16(av, bv, oa2[ii][f], 0, 0, 0);
            }
        }
    }
    __syncthreads();

    #pragma unroll
    for (int ii = 0; ii < 2; ii++){
        int i = w + ii*4;
        if (i >= 7) continue;
        #pragma unroll
        for (int f = 0; f < 12; f++){
            int m = f*16 + fr;
            #pragma unroll
            for (int r = 0; r < 4; r++){
                int nl = i*16 + kc*4 + r;
                *(bf16_t*)(lds + m*232 + nl*2) = (bf16_t)oa2[ii][f][r];
            }
        }
    }
    __syncthreads();
    const int nch = (qhalf == 0) ? 28 : 21;
    const int total = 192 * nch;
    char* ob = (char*)O + ((long)(b*192))*4736 + ((long)(h*196 + q0))*2;
    for (int idx = tid; idx < total; idx += 256){
        int m = idx / nch, ch = idx - m*nch;
        f32x2 v2 = *(const f32x2*)(lds + m*232 + ch*8);
        *(f32x2*)(ob + (long)m*4736 + ch*8) = v2;
    }
}

// ---------------- 256x256-tile MFMA GEMM, 8 waves, BK=32, triple-buffered ----
__global__ void __launch_bounds__(512, 2)
gemm256_k(const bf16_t* __restrict__ A, long ldA,
          const bf16_t* __restrict__ B, long ldB,
          bf16_t* __restrict__ C, long ldC,
          const float* __restrict__ bias1,
          int Md, int Nd, int Kd, int G, int doGelu)
{
    extern __shared__ char gsm[];           // 96 KiB: 3 bufs x (A 16K + B 16K)
    const int tid = threadIdx.x;
    const int lane = tid & 63, w = tid >> 6;
    const int wm = w >> 2, wn = w & 3;

    int gx = gridDim.x, gy = gridDim.y;
    int n2d = gx * gy;
    int flat = blockIdx.x + gx * blockIdx.y;
    int q8 = n2d >> 3, r8 = n2d & 7;
    int xcd = flat & 7, pos = flat >> 3;
    int lid = (xcd < r8 ? xcd*(q8+1) : r8*(q8+1) + (xcd-r8)*q8) + pos;
    int fullg = gx / G;
    int fullsz = fullg * G * gy;
    int bx, by;
    if (lid < fullsz){
        int gsz = G * gy;
        int g = lid / gsz, rem = lid - g*gsz;
        by = rem / G; bx = g*G + (rem - by*G);
    } else {
        int tw = gx - fullg*G;
        int rem = lid - fullsz;
        by = rem / tw; bx = fullg*G + (rem - by*tw);
    }
    const int row0 = by * 256, col0 = bx * 256;

    f32x4 acc[8][4];
    #pragma unroll
    for (int i = 0; i < 8; i++)
        #pragma unroll
        for (int j = 0; j < 4; j++)
            acc[i][j] = (f32x4){0.f, 0.f, 0.f, 0.f};

    const int fr = lane & 15, kc = lane >> 4;
    const int swz = (fr >> 1) & 3;
    int aOff[8], bOff[4];
    #pragma unroll
    for (int i = 0; i < 8; i++)
        aOff[i] = (wm*128 + i*16 + fr) * 64 + ((kc ^ swz) << 4);
    #pragma unroll
    for (int j = 0; j < 4; j++)
        bOff[j] = (wn*64 + j*16 + fr) * 64 + ((kc ^ swz) << 4);

    auto stage = [&](int buf, int kt){
        long kOff = (long)kt * 32;
        char* base = gsm + buf * 32768;
        #pragma unroll
        for (int r = 0; r < 2; r++){
            int idx = r*512 + tid;
            int row = idx >> 2, cp = idx & 3;
            int cc = cp ^ ((row >> 1) & 3);
            int ar = row0 + row; if (ar >= Md) ar = Md - 1;
            int br = col0 + row; if (br >= Nd) br = Nd - 1;
            gld16((const void*)(A + (long)ar*ldA + kOff + cc*8), (void*)(base + row*64 + cp*16));
            gld16((const void*)(B + (long)br*ldB + kOff + cc*8), (void*)(base + 16384 + row*64 + cp*16));
        }
    };

    const int nt = Kd >> 5;
    stage(0, 0);
    stage(1, 1);
    asm volatile("s_waitcnt vmcnt(4)" ::: "memory");
    __builtin_amdgcn_s_barrier();
    __builtin_amdgcn_sched_barrier(0);

    for (int t = 0; t < nt; t++){
        int cur = t % 3;
        if (t + 2 < nt) stage((t + 2) % 3, t + 2);
        const char* baseA = gsm + cur * 32768;
        const char* baseB = baseA + 16384;
        bf16x8 av[8], bv[4];
        #pragma unroll
        for (int i = 0; i < 8; i++) av[i] = *(const bf16x8*)(baseA + aOff[i]);
        #pragma unroll
        for (int j = 0; j < 4; j++) bv[j] = *(const bf16x8*)(baseB + bOff[j]);
        __builtin_amdgcn_s_setprio(1);
        #pragma unroll
        for (int i = 0; i < 8; i++)
            #pragma unroll
            for (int j = 0; j < 4; j++)
                acc[i][j] = __builtin_amdgcn_mfma_f32_16x16x32_bf16(av[i], bv[j], acc[i][j], 0, 0, 0);
        __builtin_amdgcn_s_setprio(0);
        if (t + 2 < nt)      asm volatile("s_waitcnt vmcnt(4)" ::: "memory");
        else if (t + 1 < nt) asm volatile("s_waitcnt vmcnt(0)" ::: "memory");
        __builtin_amdgcn_s_barrier();
        __builtin_amdgcn_sched_barrier(0);
    }

    #pragma unroll
    for (int i = 0; i < 8; i++){
        int gmb = row0 + wm*128 + i*16 + kc*4;
        #pragma unroll
        for (int j = 0; j < 4; j++){
            int gn = col0 + wn*64 + j*16 + fr;
            if (gn >= Nd) continue;
            float b1 = bias1 ? bias1[gn] : 0.f;
            #pragma unroll
            for (int r = 0; r < 4; r++){
                int gm = gmb + r;
                if (gm >= Md) continue;
                float v = acc[i][j][r] + b1;
                if (doGelu) v = gelu_exact(v);
                C[(long)gm*ldC + gn] = (bf16_t)v;
            }
        }
    }
}

// ---------------- MFMA bf16 GEMM: 128x128 tile, BK=32, 4 waves ----------------
// mode 0: f32 rowmajor (+Cadd, LN partials); mode 1: bf16 rowmajor;
// mode 7: split-K over z (2 halves) -> raw fp32 partial buffers.
__global__ void __launch_bounds__(256)
mfma_gemm_k(const bf16_t* __restrict__ A, long ldA, long sA,
            const bf16_t* __restrict__ B, long ldB, long sB,
            void* __restrict__ C, long ldC, long sC,
            const float* __restrict__ Cadd,
            const float* __restrict__ bias1,
            const float* __restrict__ bias2, int b2mod, int b2ld,
            int Md, int Nd, int Kd, float alpha, int doGelu, int mode,
            float* __restrict__ psum, float* __restrict__ psq, int redN, int G)
{
    __shared__ bf16_t sm[3][2][128][32];   // 48 KiB triple-buffered
    __shared__ float redbuf[8];
    const int tid = threadIdx.x;
    const int lane = tid & 63, w = tid >> 6;
    const int wm = w >> 1, wn = w & 1;
    const int z = blockIdx.z;

    long kStart = 0; int KdL = Kd; long zA = z;
    if (mode == 7){ kStart = (long)z * (Kd >> 1); KdL = Kd >> 1; zA = 0; }

    int n2d = gridDim.x * gridDim.y;
    int flat = blockIdx.x + gridDim.x * blockIdx.y;
    int q8 = n2d >> 3, r8 = n2d & 7;
    int xcd = flat & 7, pos = flat >> 3;
    int lid = (xcd < r8 ? xcd*(q8+1) : r8*(q8+1) + (xcd-r8)*q8) + pos;
    int gx = gridDim.x, gy = gridDim.y;
    int fullg = gx / G;
    int fullsz = fullg * G * gy;
    int bx, by;
    if (lid < fullsz){
        int gsz = G * gy;
        int g = lid / gsz, rem = lid - g*gsz;
        by = rem / G; bx = g*G + (rem - by*G);
    } else {
        int tw = gx - fullg*G;
        int rem = lid - fullsz;
        by = rem / tw; bx = fullg*G + (rem - by*tw);
    }

    const int row0 = by * 128, col0 = bx * 128;

    const bf16_t* Ab = A + zA * sA + (long)row0 * ldA + kStart;
    const bf16_t* Bb = B + zA * sB + (long)col0 * ldB + kStart;

    f32x4 acc[4][4];
    #pragma unroll
    for (int i = 0; i < 4; i++)
        #pragma unroll
        for (int j = 0; j < 4; j++)
            acc[i][j] = (f32x4){0.f, 0.f, 0.f, 0.f};

    const int fr = lane & 15, kc = lane >> 4;
    const int swz = (fr >> 1) & 3;
    int aOff[4], bOff[4];
    #pragma unroll
    for (int i = 0; i < 4; i++){
        aOff[i] = (wm*64 + i*16 + fr) * 64 + ((kc ^ swz) << 4);
        bOff[i] = (wn*64 + i*16 + fr) * 64 + ((kc ^ swz) << 4);
    }

    auto stage = [&](int buf, int kt){
        long kOff = (long)kt * 32;
        #pragma unroll
        for (int r = 0; r < 2; r++){
            int idx = r*256 + tid;
            int row = idx >> 2, cp = idx & 3;
            int cc = cp ^ ((row >> 1) & 3);
            gld16((const void*)(Ab + (long)row*ldA + kOff + cc*8), (void*)&sm[buf][0][row][cp*8]);
            gld16((const void*)(Bb + (long)row*ldB + kOff + cc*8), (void*)&sm[buf][1][row][cp*8]);
        }
    };

    const int nt = KdL >> 5;
    stage(0, 0);
    stage(1, 1);
    asm volatile("s_waitcnt vmcnt(4)" ::: "memory");
    __builtin_amdgcn_s_barrier();
    __builtin_amdgcn_sched_barrier(0);

    for (int t = 0; t < nt; t++){
        int cur = t % 3;
        if (t + 2 < nt) stage((t + 2) % 3, t + 2);
        const char* baseA = (const char*)sm + cur * 16384;
        const char* baseB = baseA + 8192;
        bf16x8 av[4], bv[4];
        #pragma unroll
        for (int i = 0; i < 4; i++){
            av[i] = *(const bf16x8*)(baseA + aOff[i]);
            bv[i] = *(const bf16x8*)(baseB + bOff[i]);
        }
        __builtin_amdgcn_s_setprio(1);
        #pragma unroll
        for (int i = 0; i < 4; i++)
            #pragma unroll
            for (int j = 0; j < 4; j++)
                acc[i][j] = __builtin_amdgcn_mfma_f32_16x16x32_bf16(av[i], bv[j], acc[i][j], 0, 0, 0);
        __builtin_amdgcn_s_setprio(0);
        if (t + 2 < nt)      asm volatile("s_waitcnt vmcnt(4)" ::: "memory");
        else if (t + 1 < nt) asm volatile("s_waitcnt vmcnt(0)" ::: "memory");
        __builtin_amdgcn_s_barrier();
        __builtin_amdgcn_sched_barrier(0);
    }

    float rs = 0.f, rq = 0.f;
    #pragma unroll
    for (int i = 0; i < 4; i++){
        int gmb = row0 + wm*64 + i*16 + kc*4;
        #pragma unroll
        for (int j = 0; j < 4; j++){
            int gn = col0 + wn*64 + j*16 + fr;
            if (gn >= Nd) continue;
            #pragma unroll
            for (int r = 0; r < 4; r++){
                int gm = gmb + r;
                if (gm >= Md) continue;
                float v = alpha * acc[i][j][r];
                if (bias1) v += bias1[gn];
                if (bias2) v += bias2[(long)(gm % b2mod) * b2ld + gn];
                if (doGelu) v = gelu_exact(v);
                if (mode == 0){
                    long off = (long)z*sC + (long)gm*ldC + gn;
                    if (Cadd) v += Cadd[off];
                    ((float*)C)[off] = v;
                    rs += v; rq += v*v;
                } else if (mode == 7){
                    ((float*)C)[(long)z*sC + (long)gm*ldC + gn] = v;
                } else {
                    ((bf16_t*)C)[(long)z*sC + (long)gm*ldC + gn] = (bf16_t)v;
                }
            }
        }
    }

    if (redN > 0){
        #pragma unroll
        for (int off = 32; off > 0; off >>= 1){
            rs += __shfl_xor(rs, off); rq += __shfl_xor(rq, off);
        }
        if (lane == 0){ redbuf[w] = rs; redbuf[4 + w] = rq; }
        __syncthreads();
        if (tid == 0){
            psum[flat] = redbuf[0] + redbuf[1] + redbuf[2] + redbuf[3];
            psq[flat]  = redbuf[4] + redbuf[5] + redbuf[6] + redbuf[7];
        }
    }
}

// ---------------- 64x64-tile MFMA GEMM, BK=64 (t-projection) ------
__global__ void __launch_bounds__(256)
gemm64_k(const bf16_t* __restrict__ A, long ldA, long sA,
         const bf16_t* __restrict__ B, long ldB, long sB,
         bf16_t* __restrict__ C, long ldC, long sC,
         const float* __restrict__ bias2, int b2ld,
         int Md, int Nd, int Kd)
{
    __shared__ bf16_t sm[3][2][64][64];   // 48 KiB triple-buffered, BK=64
    const int tid = threadIdx.x;
    const int lane = tid & 63, w = tid >> 6;
    const int wm = w >> 1, wn = w & 1;
    const int z = blockIdx.z;
    const int row0 = blockIdx.y * 64, col0 = blockIdx.x * 64;

    const bf16_t* Ab = A + (long)z * sA + (long)row0 * ldA;
    const bf16_t* Bb = B + (long)z * sB + (long)col0 * ldB;

    f32x4 acc[2][2];
    #pragma unroll
    for (int i = 0; i < 2; i++)
        #pragma unroll
        for (int j = 0; j < 2; j++)
            acc[i][j] = (f32x4){0.f,0.f,0.f,0.f};

    const int fr = lane & 15, kc = lane >> 4;
    int aOff[2][2], bOff[2][2];
    #pragma unroll
    for (int i = 0; i < 2; i++){
        int rowa = wm*32 + i*16 + fr;
        int rowb = wn*32 + i*16 + fr;
        #pragma unroll
        for (int s = 0; s < 2; s++){
            aOff[i][s] = rowa*128 + ((((s<<2)|kc) ^ (rowa & 7)) << 4);
            bOff[i][s] = rowb*128 + ((((s<<2)|kc) ^ (rowb & 7)) << 4);
        }
    }

    auto stage = [&](int buf, int kt){
        long kOff = (long)kt * 64;
        #pragma unroll
        for (int r = 0; r < 2; r++){
            int idx = r*256 + tid;
            int row = idx >> 3, cp = idx & 7;
            int cc = cp ^ (row & 7);
            gld16((const void*)(Ab + (long)row*ldA + kOff + cc*8), (void*)&sm[buf][0][row][cp*8]);
            gld16((const void*)(Bb + (long)row*ldB + kOff + cc*8), (void*)&sm[buf][1][row][cp*8]);
        }
    };

    const int nt = Kd >> 6;    // BK=64
    stage(0, 0);
    stage(1, 1);
    asm volatile("s_waitcnt vmcnt(4)" ::: "memory");
    __builtin_amdgcn_s_barrier();
    __builtin_amdgcn_sched_barrier(0);

    for (int t = 0; t < nt; t++){
        int cur = t % 3;
        if (t + 2 < nt) stage((t + 2) % 3, t + 2);
        const char* baseA = (const char*)sm + cur * 16384;
        const char* baseB = baseA + 8192;
        __builtin_amdgcn_s_setprio(1);
        #pragma unroll
        for (int s = 0; s < 2; s++){
            bf16x8 av0 = *(const bf16x8*)(baseA + aOff[0][s]);
            bf16x8 av1 = *(const bf16x8*)(baseA + aOff[1][s]);
            bf16x8 bv0 = *(const bf16x8*)(baseB + bOff[0][s]);
            bf16x8 bv1 = *(const bf16x8*)(baseB + bOff[1][s]);
            acc[0][0] = __builtin_amdgcn_mfma_f32_16x16x32_bf16(av0, bv0, acc[0][0], 0, 0, 0);
            acc[0][1] = __builtin_amdgcn_mfma_f32_16x16x32_bf16(av0, bv1, acc[0][1], 0, 0, 0);
            acc[1][0] = __builtin_amdgcn_mfma_f32_16x16x32_bf16(av1, bv0, acc[1][0], 0, 0, 0);
            acc[1][1] = __builtin_amdgcn_mfma_f32_16x16x32_bf16(av1, bv1, acc[1][1], 0, 0, 0);
        }
        __builtin_amdgcn_s_setprio(0);
        if (t + 2 < nt)      asm volatile("s_waitcnt vmcnt(4)" ::: "memory");
        else if (t + 1 < nt) asm volatile("s_waitcnt vmcnt(0)" ::: "memory");
        __builtin_amdgcn_s_barrier();
        __builtin_amdgcn_sched_barrier(0);
    }

    #pragma unroll
    for (int i = 0; i < 2; i++){
        int gmb = row0 + wm*32 + i*16 + kc*4;
        #pragma unroll
        for (int j = 0; j < 2; j++){
            int gn = col0 + wn*32 + j*16 + fr;
            if (gn >= Nd) continue;
            #pragma unroll
            for (int r = 0; r < 4; r++){
                int gm = gmb + r;
                if (gm >= Md) continue;
                float v = acc[i][j][r];
                if (bias2) v += bias2[(long)gm * b2ld + gn];
                C[(long)z*sC + (long)gm*ldC + gn] = (bf16_t)v;
            }
        }
    }
}

// ---------------- head: [32 x 150528] @ [150528 x 512] fp32, split-K ----------------
__global__ void __launch_bounds__(256)
head_splitk_k(const float* __restrict__ A, const float* __restrict__ W, float* __restrict__ feat)
{
    __shared__ float As[16][36];
    __shared__ float Bs[16][68];
    int col0 = blockIdx.x * 64;
    long kbase = (long)blockIdx.y * 2352;
    int tid = threadIdx.x, tx = tid & 15, ty = tid >> 4;
    float acc[2][4] = {};
    for (int k0 = 0; k0 < 2352; k0 += 16){
        #pragma unroll
        for (int u = 0; u < 2; u++){
            int idx = tid * 2 + u;
            int m = idx >> 4, kk = idx & 15;
            As[kk][m] = A[(long)m * KHEAD + kbase + k0 + kk];
        }
        #pragma unroll
        for (int u = 0; u < 4; u++){
            int idx = tid * 4 + u;
            int kk = idx >> 6, n = idx & 63;
            Bs[kk][n] = W[(kbase + k0 + kk) * 512 + col0 + n];
        }
        __syncthreads();
        #pragma unroll
        for (int kk = 0; kk < 16; kk++){
            float a0 = As[kk][ty*2], a1 = As[kk][ty*2+1];
            float b0 = Bs[kk][tx*4], b1 = Bs[kk][tx*4+1], b2 = Bs[kk][tx*4+2], b3 = Bs[kk][tx*4+3];
            acc[0][0] += a0*b0; acc[0][1] += a0*b1; acc[0][2] += a0*b2; acc[0][3] += a0*b3;
            acc[1][0] += a1*b0; acc[1][1] += a1*b1; acc[1][2] += a1*b2; acc[1][3] += a1*b3;
        }
        __syncthreads();
    }
    #pragma unroll
    for (int i = 0; i < 2; i++)
        #pragma unroll
        for (int j = 0; j < 4; j++)
            atomicAdd(&feat[(ty*2 + i) * 512 + col0 + tx*4 + j], acc[i][j]);
}

// cls with fused gelu(feat + head_b)
__global__ void __launch_bounds__(256)
cls_k(const float* __restrict__ feat, const float* __restrict__ hb,
      const float* __restrict__ W, const float* __restrict__ bias, float* __restrict__ out)
{
    __shared__ float fs[512];
    int b = blockIdx.y;
    int j = blockIdx.x * 256 + threadIdx.x;
    for (int i = threadIdx.x; i < 512; i += 256)
        fs[i] = gelu_exact(feat[b * 512 + i] + hb[i]);
    __syncthreads();
    if (j < NCLS){
        float s = bias[j];
        for (int k = 0; k < 512; k++) s += fs[k] * W[(long)k * NCLS + j];
        out[b * NCLS + j] = s;
    }
}

// ---------------- launch ----------------
extern "C" void kernel_launch(void* const* d_in, const int* in_sizes, int n_in,
                              void* d_out, int out_size, void* d_ws, size_t ws_size,
                              hipStream_t stream)
{
    const float* image   = (const float*)d_in[0];
    const float* patch_w = (const float*)d_in[1];
    const float* patch_b = (const float*)d_in[2];
    const float* pos_emb = (const float*)d_in[3];
    const float* qw  = (const float*)d_in[4];
    const float* qb  = (const float*)d_in[5];
    const float* kw  = (const float*)d_in[6];
    const float* kb  = (const float*)d_in[7];
    const float* vw  = (const float*)d_in[8];
    const float* vb  = (const float*)d_in[9];
    const float* ow1 = (const float*)d_in[10];
    const float* ob1 = (const float*)d_in[11];
    const float* ow2 = (const float*)d_in[12];
    const float* ob2 = (const float*)d_in[13];
    const float* d1w = (const float*)d_in[14];
    const float* d1b = (const float*)d_in[15];
    const float* d2w = (const float*)d_in[16];
    const float* d2b = (const float*)d_in[17];
    const float* head_w = (const float*)d_in[18];
    const float* head_b = (const float*)d_in[19];
    const float* cls_w  = (const float*)d_in[20];
    const float* cls_b  = (const float*)d_in[21];

    char* wsb = (char*)d_ws;
    float*  X    = (float*) (wsb + OB_X);
    float*  R    = (float*) (wsb + OB_R);
    bf16_t* XB   = (bf16_t*)(wsb + OB_XB);
    bf16_t* XQKV = (bf16_t*)(wsb + OB_XQKV);
    float*  P0   = (float*) (wsb + OB_P0);
    bf16_t* VT   = (bf16_t*)(wsb + OB_VT);
    bf16_t* O    = (bf16_t*)(wsb + OB_O);
    bf16_t* Tt   = (bf16_t*)(wsb + OB_T);
    bf16_t* H1   = XQKV;
    bf16_t* PATB = XQKV;
    bf16_t* WQKV = (bf16_t*)(wsb + OB_WQKV);
    bf16_t* WO1  = (bf16_t*)(wsb + OB_WO1);
    bf16_t* WO2  = (bf16_t*)(wsb + OB_WO2);
    bf16_t* WD1  = (bf16_t*)(wsb + OB_WD1);
    bf16_t* WD2  = (bf16_t*)(wsb + OB_WD2);
    bf16_t* WPAT = (bf16_t*)(wsb + OB_WPAT);
    float*  BQKV = (float*) (wsb + OB_BQKV);
    float*  OB1T = (float*) (wsb + OB_OB1T);
    float*  PS   = (float*) (wsb + OB_RED);
    float*  PQ   = PS + NPARTF;
    float*  FEAT = (float*) (wsb + OB_FEAT);
    float*  out  = (float*)d_out;

    hipFuncSetAttribute((const void*)attn_fused_k,
                        hipFuncAttributeMaxDynamicSharedMemorySize, ATTN_LDS);
    hipFuncSetAttribute((const void*)gemm256_k,
                        hipFuncAttributeMaxDynamicSharedMemorySize, G256_LDS);

    auto pickG = [](int Kd){
        int g = (3*1024*1024) / (128 * Kd * 2);
        if (g > 8) g = 8;
        if (g < 1) g = 1;
        return g;
    };
    auto mg = [&](const bf16_t* A, long ldA, long sA, const bf16_t* B, long ldB, long sB,
                  void* C, long ldC, long sC, const float* Cadd, const float* b1,
                  const float* b2, int b2mod, int b2ld,
                  int Md, int Nd, int Kd, int nb, float alpha, int gelu, int mode, int redN){
        dim3 g((Nd + 127) / 128, (Md + 127) / 128, nb);
        mfma_gemm_k<<<g, 256, 0, stream>>>(A, ldA, sA, B, ldB, sB, C, ldC, sC,
                                           Cadd, b1, b2, b2mod, b2ld,
                                           Md, Nd, Kd, alpha, gelu, mode, PS, PQ, redN,
                                           pickG(Kd));
    };
    auto wconv = [&](const float* in, bf16_t* o_, int IR, int IC, int perm, long OLD,
                     int padTo, int nz, long inZ, long outZ){
        dim3 g((IC + 31) / 32, (padTo + 31) / 32, nz);
        wconv_k<<<g, 256, 0, stream>>>(in, o_, IR, IC, OLD, perm, padTo, inZ, outZ);
    };
    auto lnapply = [&](const float* in, bf16_t* ob, float* of, int npart){
        ln_apply_k<<<4704, 256, 0, stream>>>(in, ob, of, PS, PQ, npart);
    };

    // ---- bulk weight conversion (all layers upfront) ----
    wconv(patch_w, WPAT, 768, 768, 0, 768, 768, 1, 0, 0);
    wconv(qw, WQKV,               768, 2304, 1, 768, 768, 6, 768L*2304, 6912L*768);
    wconv(kw, WQKV + 2304L*768,   768, 2304, 1, 768, 768, 6, 768L*2304, 6912L*768);
    wconv(vw, WQKV + 4608L*768,   768, 2304, 1, 768, 768, 6, 768L*2304, 6912L*768);
    wconv(ow1, WO1, 2352, 196, 0, 2368, 2368, 6, 2352L*196, 606208L);
    wconv(ow2, WO2, 192, 768, 0, 192, 192, 6, 147456L, 147456L);
    wconv(d1w, WD1, 768, 3072, 0, 768, 768, 6, 2359296L, 2359296L);
    wconv(d2w, WD2, 3072, 768, 0, 3072, 3072, 6, 2359296L, 2359296L);
    gather_bias_k<<<dim3(27, 6), 256, 0, stream>>>(qb, kb, vb, BQKV);
    tr_bias_k<<<dim3(147, 6), 256, 0, stream>>>(ob1, OB1T);

    // ---- patch encode (writes X + LN partials, grid 294) ----
    patch_extract_k<<<18816, 256, 0, stream>>>(image, PATB);
    mg(PATB, 768, 0, WPAT, 768, 0, X, 768, 0,
       nullptr, patch_b, pos_emb, 196, 768, 6272, 768, 768, 1, 1.f, 0, 0, NPART);
    zero_pad_o_k<<<384, 256, 0, stream>>>(O);

    for (int l = 0; l < NLAY; l++){
        lnapply(X, XB, nullptr, l == 0 ? NPART : NPARTF);            // x1
        // QKV: 256x256-tile kernel, row-major [6272][6912]
        gemm256_k<<<dim3(27, 25), 512, G256_LDS, stream>>>(
            XB, 768, WQKV + (long)l*6912*768, 768, XQKV, 6912,
            BQKV + l*6912, 6272, 6912, 768, 8, 0);
        tr_v_k<<<dim3(6, 7, 384), 256, 0, stream>>>(XQKV, VT);
        attn_fused_k<<<dim3(2, 384), 256, ATTN_LDS, stream>>>(XQKV, VT, O);
        // t[b][n][m] = ow1^T_n . o_b_m + ob1^T  (64x64 tiles, BK=64, 384 blocks)
        gemm64_k<<<dim3(3, 4, 32), 256, 0, stream>>>(
            WO1 + (long)l*606208, 2368, 0, O, 2368, 192L*2368, Tt, 192, 37632,
            OB1T + (long)l*37632, 192, 196, 192, 2368);
        // x2 = t @ ow2 + ob2 + X -> R  (grid 294, LN partials)
        mg(Tt, 192, 0, WO2 + (long)l*147456, 192, 0, R, 768, 0, X, nullptr,
           ob2 + (long)l*196*768, 196, 768, 6272, 768, 192, 1, 1.f, 0, 0, NPART);
        lnapply(R, XB, nullptr, NPART);                              // x3
        // FFN1: 128x128 tiles (1176 blocks), gelu fused
        mg(XB, 768, 0, WD1 + (long)l*2359296, 768, 0, H1, 3072, 0, nullptr,
           d1b + l*3072, nullptr, 1, 1, 6272, 3072, 768, 1, 1.f, 1, 1, 0);
        // FFN2 split-K=2 -> fp32 partials (588 blocks), then fused finish
        mg(H1, 3072, 0, WD2 + (long)l*2359296, 3072, 0, P0, 768, 4816896, nullptr,
           nullptr, nullptr, 1, 1, 6272, 768, 3072, 2, 1.f, 0, 7, 0);
        ffn2_finish_k<<<4704, 256, 0, stream>>>(P0, R, d2b + l*768, X, PS, PQ);
    }

    lnapply(X, XB, R, NPARTF);                                       // final LN -> R fp32
    hipMemsetAsync(FEAT, 0, BZ * HEADU * sizeof(float), stream);
    head_splitk_k<<<dim3(8, 64), 256, 0, stream>>>(R, head_w, FEAT);
    cls_k<<<dim3(4, 32), 256, 0, stream>>>(FEAT, head_b, cls_w, cls_b, out);
    (void)in_sizes; (void)n_in; (void)out_size; (void)ws_size;
}